// Round 18
// baseline (63.240 us; speedup 1.0000x reference)
//
#include <hip/hip_runtime.h>

// 5-level wavedec (filter len 8, pywt 'symmetric'), 4096 rows of 8192 f32.
// Lengths: 8192 -> 4099 -> 2053 -> 1030 -> 518 -> 262
// Out: approx(262) @0, d5(262), d4(518), d3(1030), d2(2053), d1(4099).
//
// R18 = R10/R14 (best, 58.4us) + T2-style XOR swizzle on the LDS a-buffers
// at float2-slot granularity: phys_slot = slot ^ ((slot>>2)&15).
// Window reads (lane slot-stride 4 -> 16-way bank conflict, 5.7x) become a
// perfect 16-position permutation -> b64 4-way hardware floor (~free).
// Unlike R4 (pad-per-8 -> scalar reads) this keeps every access b64.
// Swizzle applied on BOTH write and read sides; global paths untouched.

static constexpr int ROWS = 4096;
static constexpr int N0 = 8192;
static constexpr int L1n = 4099, L2n = 2053, L3n = 1030, L4n = 518, L5n = 262;
static constexpr size_t OFF_D5 = 1073152u;
static constexpr size_t OFF_D4 = 2146304u;
static constexpr size_t OFF_D3 = 4268032u;
static constexpr size_t OFF_D2 = 8486912u;
static constexpr size_t OFF_D1 = 16896000u;

// float2-slot swizzle: keeps pairs {2j,2j+1} in one aligned b64, spreads
// lane-stride-4 slot patterns across all 16 bank-pair positions.
__device__ __forceinline__ int swzs(int slot) { return slot ^ ((slot >> 2) & 15); }

// Barrier ordering LDS only (no vmcnt drain of global d-stores).
__device__ __forceinline__ void barrier_lds() {
    asm volatile("s_waitcnt lgkmcnt(0)\n\ts_barrier" ::: "memory");
}

__device__ __forceinline__ int refl_idx(int idx, int n) {
    return (idx < 0) ? (-1 - idx) : ((idx >= n) ? (2 * n - 1 - idx) : idx);
}

// scalar load honoring optional swizzle (for edge paths)
template <bool SWZ>
__device__ __forceinline__ float src_load(const float* __restrict__ s, int fidx) {
    if constexpr (SWZ) return s[2 * swzs(fidx >> 1) + (fidx & 1)];
    else               return s[fidx];
}

// Clamped 16-float window load for group j: w[t] = src[8j-6+t]
template <int N, bool SWZ>
__device__ __forceinline__ void load_window(const float* __restrict__ src,
                                            int j, float* __restrict__ w) {
    constexpr int jmax = (N - 10) >> 3;
    const int jb = j < 1 ? 1 : (j > jmax ? jmax : j);
    if constexpr (SWZ) {
#pragma unroll
        for (int t = 0; t < 8; ++t) {
            const int slot = 4 * jb - 3 + t;
            const float2 v = *reinterpret_cast<const float2*>(src + 2 * swzs(slot));
            w[2 * t] = v.x; w[2 * t + 1] = v.y;
        }
    } else {
        const float2* __restrict__ s2 =
            reinterpret_cast<const float2*>(src) + (4 * jb - 3);
#pragma unroll
        for (int t = 0; t < 8; ++t) {
            const float2 v = s2[t];
            w[2 * t] = v.x; w[2 * t + 1] = v.y;
        }
    }
}

// Branchy symmetric-reflect path for edge / partial groups.
template <int N, int M, bool SWZS_, bool SWZA>
__device__ __forceinline__ void edge_group(
    const float* __restrict__ src,
    const float* __restrict__ h, const float* __restrict__ g,
    float* __restrict__ adst, float* __restrict__ ddst, int j)
{
#pragma unroll 4
    for (int r = 0; r < 4; ++r) {
        const int pos = 4 * j + r;
        if (pos >= M) break;
        const int s0 = 2 * pos + 1;
        float a = 0.f, d = 0.f;
#pragma unroll
        for (int q = 0; q < 8; ++q) {
            const float v = src_load<SWZS_>(src, refl_idx(s0 - q, N));
            a = fmaf(h[q], v, a);
            d = fmaf(g[q], v, d);
        }
        ddst[pos] = d;
        if constexpr (SWZA) adst[2 * swzs(pos >> 1) + (pos & 1)] = a;
        else                adst[pos] = a;
    }
}

// One DWT level, NITER windows loaded upfront (R10-proven form).
template <int N, int M, int NITER, bool SWZS_, bool SWZA>
__device__ __forceinline__ void dwt_level(
    const float* __restrict__ src,
    const float* __restrict__ h, const float* __restrict__ g,
    float* __restrict__ adst, float* __restrict__ ddst, int tid)
{
    constexpr int ngroups = (M + 3) >> 2;
    constexpr int jmax = (N - 10) >> 3;
    constexpr int rem = ngroups - NITER * 256;       // leftover (edge) groups
    constexpr bool full = (NITER * 256 <= ngroups);  // all t-slots valid

    float w[NITER][16];
#pragma unroll
    for (int t = 0; t < NITER; ++t) {
        const int j = tid + t * 256;
        if (full || j < ngroups)
            load_window<N, SWZS_>(src, j, &w[t][0]);
    }
    __builtin_amdgcn_sched_barrier(0);

#pragma unroll
    for (int t = 0; t < NITER; ++t) {
        const int j = tid + t * 256;
        if (!full && j >= ngroups) break;
        const int p0 = 4 * j;
        if (j >= 1 && j <= jmax && p0 + 3 < M) {
            float aa[4], dd[4];
#pragma unroll
            for (int r = 0; r < 4; ++r) {
                float a = 0.f, d = 0.f;
#pragma unroll
                for (int q = 0; q < 8; ++q) {
                    const float v = w[t][2 * r + 7 - q];   // src[2(p0+r)+1-q]
                    a = fmaf(h[q], v, a);
                    d = fmaf(g[q], v, d);
                }
                aa[r] = a; dd[r] = d;
            }
#pragma unroll
            for (int r = 0; r < 4; ++r) ddst[p0 + r] = dd[r];
            if constexpr (SWZA) {
                float2* __restrict__ b2 = reinterpret_cast<float2*>(adst);
                float2 v0; v0.x = aa[0]; v0.y = aa[1];
                float2 v1; v1.x = aa[2]; v1.y = aa[3];
                b2[swzs(2 * j)]     = v0;
                b2[swzs(2 * j + 1)] = v1;
            } else {
#pragma unroll
                for (int r = 0; r < 4; ++r) adst[p0 + r] = aa[r];
            }
        } else {
            edge_group<N, M, SWZS_, SWZA>(src, h, g, adst, ddst, j);
        }
    }
    if constexpr (rem > 0) {
        if (tid < rem)
            edge_group<N, M, SWZS_, SWZA>(src, h, g, adst, ddst, NITER * 256 + tid);
    }
}

__global__ __launch_bounds__(256, 4)
void wavedec5_kernel(const float* __restrict__ x,
                     const float* __restrict__ dlo,
                     const float* __restrict__ dhi,
                     float* __restrict__ out)
{
    // padded for swizzle range: slots | 15
    __shared__ __align__(16) float bufA[4128];  // a1 / a3 (2064 slots)
    __shared__ __align__(16) float bufB[2080];  // a2 / a4 (1040 slots)

    const int row = blockIdx.x;
    const int tid = threadIdx.x;

    float h[8], g[8];
#pragma unroll
    for (int i = 0; i < 8; ++i) { h[i] = dlo[i]; g[i] = dhi[i]; }

    const float* __restrict__ xr = x + (size_t)row * N0;

    // L1: global(x, no swz) -> bufA(swz), d1 -> global
    dwt_level<N0, L1n, 4, false, true>(xr, h, g, bufA,
                          out + OFF_D1 + (size_t)row * L1n, tid);
    barrier_lds();
    // L2: bufA(swz) -> bufB(swz), d2 -> global
    dwt_level<L1n, L2n, 2, true, true>(bufA, h, g, bufB,
                           out + OFF_D2 + (size_t)row * L2n, tid);
    barrier_lds();
    // L3: bufB(swz) -> bufA(swz), d3 -> global
    dwt_level<L2n, L3n, 1, true, true>(bufB, h, g, bufA,
                           out + OFF_D3 + (size_t)row * L3n, tid);
    barrier_lds();
    // L4: bufA(swz) -> bufB(swz), d4 -> global
    dwt_level<L3n, L4n, 1, true, true>(bufA, h, g, bufB,
                           out + OFF_D4 + (size_t)row * L4n, tid);
    barrier_lds();
    // L5: bufB(swz) -> approx(global, no swz) & d5(global)
    dwt_level<L4n, L5n, 1, true, false>(bufB, h, g,
                           out + (size_t)row * L5n,
                           out + OFF_D5 + (size_t)row * L5n, tid);
}

extern "C" void kernel_launch(void* const* d_in, const int* in_sizes, int n_in,
                              void* d_out, int out_size, void* d_ws, size_t ws_size,
                              hipStream_t stream) {
    const float* x   = (const float*)d_in[0];
    const float* dlo = (const float*)d_in[1];
    const float* dhi = (const float*)d_in[2];
    float* out = (float*)d_out;
    wavedec5_kernel<<<ROWS, 256, 0, stream>>>(x, dlo, dhi, out);
}